// Round 10
// baseline (120.788 us; speedup 1.0000x reference)
//
#include <hip/hip_runtime.h>
#include <hip/hip_bf16.h>
#include <stdint.h>

#define C_DIM 512
#define T_SEQ 8192
#define N_PROP 16384
#define HID_DIM 1024
#define OUT_DIM 512
#define K2C 1024  // 2*C

typedef __attribute__((ext_vector_type(8))) __bf16 bf16x8;
typedef __attribute__((ext_vector_type(4))) float f32x4;

// ---------------- cumsum: one wave per channel, float4 chunks, shuffle scan ----------------
__global__ __launch_bounds__(64) void cumsum_kernel(const float* __restrict__ feat,
                                                    float* __restrict__ cs_inc) {
    int c = blockIdx.x;
    const float4* in = (const float4*)(feat + (size_t)c * T_SEQ);
    float4* out = (float4*)(cs_inc + (size_t)c * T_SEQ);
    int lane = threadIdx.x;
    float carry = 0.0f;
    for (int i0 = 0; i0 < T_SEQ / 4; i0 += 64) {
        float4 v = in[i0 + lane];
        float s1 = v.x + v.y;
        float s2 = s1 + v.z;
        float s3 = s2 + v.w;
        float x = s3;
#pragma unroll
        for (int s = 1; s < 64; s <<= 1) {
            float y = __shfl_up(x, s);
            if (lane >= s) x += y;
        }
        float base = carry + (x - s3);
        float4 o;
        o.x = base + v.x; o.y = base + s1; o.z = base + s2; o.w = base + s3;
        out[i0 + lane] = o;
        carry += __shfl(x, 63);
    }
}

// ---------------- transpose cs_inc (C, T) -> cs_t (T+1, C) with leading-zero shift ----------------
__global__ __launch_bounds__(256) void transpose_kernel(const float* __restrict__ cs_inc,
                                                        float* __restrict__ cs_t) {
    __shared__ float tl[32][33];
    int tx = threadIdx.x, ty = threadIdx.y;  // (32, 8)
    int x0 = blockIdx.x * 32;
    int y0 = blockIdx.y * 32;
#pragma unroll
    for (int i = 0; i < 32; i += 8) {
        int t = x0 + tx;
        int ch = y0 + ty + i;
        float v = 0.0f;
        if (t >= 1 && t <= T_SEQ) v = cs_inc[(size_t)ch * T_SEQ + (t - 1)];
        tl[ty + i][tx] = v;
    }
    __syncthreads();
#pragma unroll
    for (int i = 0; i < 32; i += 8) {
        int t = x0 + ty + i;
        int ch = y0 + tx;
        if (t <= T_SEQ) cs_t[(size_t)t * C_DIM + ch] = tl[tx][ty + i];
    }
}

// ---------------- pooling -> e (N, 2C) bf16; 4 proposals/block, float4/thread ----------------
__global__ __launch_bounds__(512) void pool_kernel(const float* __restrict__ cs_t,
                                                   const int* __restrict__ lptr,
                                                   const int* __restrict__ rptr,
                                                   __hip_bfloat16* __restrict__ e) {
    int n = blockIdx.x * 4 + (threadIdx.x >> 7);
    int c4 = (threadIdx.x & 127) * 4;
    int li = lptr[n], ri = rptr[n];
    float w = fmaxf((float)(ri - li), 1.0f);
    int bw = max(1, (int)(0.15f * w));
    int lb_s = max(0, li - bw);
    int lb_e = min(T_SEQ, li + bw);
    int rb_s = max(0, ri - bw);
    int rb_e = min(T_SEQ, ri + bw);
    lb_e = min(max(lb_s + 1, lb_e), T_SEQ);
    rb_e = min(max(rb_s + 1, rb_e), T_SEQ);
    float4 a = *(const float4*)(cs_t + (size_t)lb_e * C_DIM + c4);
    float4 b = *(const float4*)(cs_t + (size_t)lb_s * C_DIM + c4);
    float4 cc = *(const float4*)(cs_t + (size_t)rb_e * C_DIM + c4);
    float4 d = *(const float4*)(cs_t + (size_t)rb_s * C_DIM + c4);
    float rl = 1.0f / (float)(lb_e - lb_s);
    float rr = 1.0f / (float)(rb_e - rb_s);
    __hip_bfloat16 L0 = __float2bfloat16((a.x - b.x) * rl);
    __hip_bfloat16 L1 = __float2bfloat16((a.y - b.y) * rl);
    __hip_bfloat16 L2 = __float2bfloat16((a.z - b.z) * rl);
    __hip_bfloat16 L3 = __float2bfloat16((a.w - b.w) * rl);
    __hip_bfloat16 R0 = __float2bfloat16((cc.x - d.x) * rr);
    __hip_bfloat16 R1 = __float2bfloat16((cc.y - d.y) * rr);
    __hip_bfloat16 R2 = __float2bfloat16((cc.z - d.z) * rr);
    __hip_bfloat16 R3 = __float2bfloat16((cc.w - d.w) * rr);
    ushort4 ul, ur;
    ul.x = *(unsigned short*)&L0; ul.y = *(unsigned short*)&L1;
    ul.z = *(unsigned short*)&L2; ul.w = *(unsigned short*)&L3;
    ur.x = *(unsigned short*)&R0; ur.y = *(unsigned short*)&R1;
    ur.z = *(unsigned short*)&R2; ur.w = *(unsigned short*)&R3;
    *(ushort4*)(e + (size_t)n * K2C + c4) = ul;
    *(ushort4*)(e + (size_t)n * K2C + C_DIM + c4) = ur;
}

// ---------------- fused fp32 -> bf16 convert for W1 and W2 ----------------
__global__ __launch_bounds__(256) void cvt_bf16_kernel(const float* __restrict__ W1,
                                                       const float* __restrict__ W2,
                                                       __hip_bfloat16* __restrict__ W1b,
                                                       __hip_bfloat16* __restrict__ W2b) {
    const int n1 = HID_DIM * K2C;
    int i = (blockIdx.x * 256 + threadIdx.x) * 4;
    const float* src;
    __hip_bfloat16* dst;
    int j;
    if (i < n1) { src = W1; dst = W1b; j = i; }
    else        { src = W2; dst = W2b; j = i - n1; }
    float4 v = *(const float4*)(src + j);
    __hip_bfloat16 h0 = __float2bfloat16(v.x);
    __hip_bfloat16 h1 = __float2bfloat16(v.y);
    __hip_bfloat16 h2 = __float2bfloat16(v.z);
    __hip_bfloat16 h3 = __float2bfloat16(v.w);
    ushort4 u;
    u.x = *(unsigned short*)&h0; u.y = *(unsigned short*)&h1;
    u.z = *(unsigned short*)&h2; u.w = *(unsigned short*)&h3;
    *(ushort4*)(dst + j) = u;
}

// ---------------- high-intensity dbuf GEMM (R6 schedule, tall tiles) ----------------
// C[m][n] = sum_k A[m][k]*B[n][k] (+bias, optional relu->bf16). BK=32, 512 thr = 8 waves.
// R6-proven loop (best measured GEMM): stage(t+1 -> buf^1) FIRST, then ds_read(buf),
// MFMA, __syncthreads (its vmcnt0+barrier is optimal for a 2-slot ring).
// Geometry change vs R6: taller tiles raise arithmetic intensity (staged bytes/step
// prop. BM+BN, MFMA/step prop. BM*BN) while keeping 16 waves/CU (2 blocks/CU x 8 waves).
// GEMM1: 256x128 (waves 4Mx2N, wave 64x64). GEMM2: 256x64 (waves 8Mx1N, wave 32x64).
// Staging: 64B rows (BK=32), 16B granules; both-sides swizzle sigma(row)=row&3
// (linear LDS dest + pre-swizzled global source + same XOR on ds_read; rule-21).
template <int BM, int BN, int WM, int WN, int K, int RELU_BF16>
__global__ __launch_bounds__(512, 2) void gemm_hi_kernel(const __hip_bfloat16* __restrict__ A,
                                                         const __hip_bfloat16* __restrict__ B,
                                                         const float* __restrict__ bias,
                                                         void* __restrict__ Cout,
                                                         int Nc, int NBlk) {
    constexpr int BK = 32;
    constexpr int NT = K / BK;
    constexpr int WMT = BM / WM, WNT = BN / WN;
    constexpr int MR = WMT / 16, NR = WNT / 16;
    constexpr int RA = BM / 128;          // full 8KB staging rounds for A
    constexpr int RB = BN / 128;          // full rounds for B
    constexpr bool BHALF = (BN % 128) == 64;  // half-round (first 4 waves)

    __shared__ __align__(16) __hip_bfloat16 As[2][BM * BK];
    __shared__ __align__(16) __hip_bfloat16 Bs[2][BN * BK];

    const int tid = threadIdx.x;
    const int lane = tid & 63;
    const int wid = tid >> 6;
    const int wm = wid / WN;
    const int wn = wid % WN;

    const int nwg = gridDim.x;  // 512 (multiple of 8)
    const int wg = (blockIdx.x & 7) * (nwg >> 3) + (blockIdx.x >> 3);
    const long m0 = (long)(wg / NBlk) * BM;
    const long n0 = (long)(wg % NBlk) * BN;

    const int srow = tid >> 2;                  // staging row within 128-row round
    const int sgsw = (tid & 3) ^ (srow & 3);    // pre-swizzled 16B source granule
    const int fr = lane & 15;
    const int gq = lane >> 4;                   // logical granule 0..3

    f32x4 acc[MR][NR] = {};

    auto stage = [&](int s, int k0) {
#pragma unroll
        for (int i = 0; i < RA; ++i)
            __builtin_amdgcn_global_load_lds(
                (const __attribute__((address_space(1))) void*)(A + (m0 + i * 128 + srow) * K + k0 + sgsw * 8),
                (__attribute__((address_space(3))) void*)(&As[s][i * 4096 + tid * 8]), 16, 0, 0);
#pragma unroll
        for (int i = 0; i < RB; ++i)
            __builtin_amdgcn_global_load_lds(
                (const __attribute__((address_space(1))) void*)(B + (n0 + i * 128 + srow) * K + k0 + sgsw * 8),
                (__attribute__((address_space(3))) void*)(&Bs[s][i * 4096 + tid * 8]), 16, 0, 0);
        if constexpr (BHALF) {
            if (tid < 256)  // waves 0-3; srow 0..63 covers the 64 B-rows
                __builtin_amdgcn_global_load_lds(
                    (const __attribute__((address_space(1))) void*)(B + (n0 + srow) * K + k0 + sgsw * 8),
                    (__attribute__((address_space(3))) void*)(&Bs[s][tid * 8]), 16, 0, 0);
        }
    };
    auto ldA = [&](int s, int row) -> bf16x8 {
        return *(const bf16x8*)(&As[s][row * BK + ((gq ^ (row & 3)) * 8)]);
    };
    auto ldB = [&](int s, int row) -> bf16x8 {
        return *(const bf16x8*)(&Bs[s][row * BK + ((gq ^ (row & 3)) * 8)]);
    };

    stage(0, 0);
    __syncthreads();
    for (int t = 0; t < NT; ++t) {
        const int cur = t & 1;
        if (t + 1 < NT) stage(cur ^ 1, (t + 1) * BK);
        bf16x8 af[MR], bv[NR];
#pragma unroll
        for (int m = 0; m < MR; ++m) af[m] = ldA(cur, wm * WMT + m * 16 + fr);
#pragma unroll
        for (int n = 0; n < NR; ++n) bv[n] = ldB(cur, wn * WNT + n * 16 + fr);
#pragma unroll
        for (int m = 0; m < MR; ++m)
#pragma unroll
            for (int n = 0; n < NR; ++n)
                acc[m][n] = __builtin_amdgcn_mfma_f32_16x16x32_bf16(af[m], bv[n], acc[m][n], 0, 0, 0);
        __syncthreads();
    }

    const int rq = (lane >> 4) * 4;
#pragma unroll
    for (int m = 0; m < MR; ++m)
#pragma unroll
        for (int n = 0; n < NR; ++n) {
            long col = n0 + wn * WNT + n * 16 + fr;
            float bb = bias[col];
#pragma unroll
            for (int q = 0; q < 4; ++q) {
                long row = m0 + wm * WMT + m * 16 + rq + q;
                float v = acc[m][n][q] + bb;
                if (RELU_BF16) {
                    v = fmaxf(v, 0.0f);
                    ((__hip_bfloat16*)Cout)[row * Nc + col] = __float2bfloat16(v);
                } else {
                    ((float*)Cout)[row * Nc + col] = v;
                }
            }
        }
}

extern "C" void kernel_launch(void* const* d_in, const int* in_sizes, int n_in,
                              void* d_out, int out_size, void* d_ws, size_t ws_size,
                              hipStream_t stream) {
    const float* feat = (const float*)d_in[0];
    const int* l = (const int*)d_in[1];
    const int* r = (const int*)d_in[2];
    const float* W1 = (const float*)d_in[4];
    const float* b1 = (const float*)d_in[5];
    const float* W2 = (const float*)d_in[6];
    const float* b2 = (const float*)d_in[7];

    char* ws = (char*)d_ws;
    float* cs_t = (float*)ws;                                    // 8193*512*4
    __hip_bfloat16* e = (__hip_bfloat16*)(ws + 16779264);        // 16384*1024*2
    __hip_bfloat16* h = (__hip_bfloat16*)(ws + 50333696);        // 16384*1024*2 (aliases cs_inc)
    float* cs_inc = (float*)(ws + 50333696);                     // 512*8192*4, dead before h
    __hip_bfloat16* W1b = (__hip_bfloat16*)(ws + 83888128);      // 1024*1024*2
    __hip_bfloat16* W2b = (__hip_bfloat16*)(ws + 85985280);      // 512*1024*2

    const int ncvt = (HID_DIM * K2C + OUT_DIM * HID_DIM) / 4 / 256;
    cvt_bf16_kernel<<<dim3(ncvt), 256, 0, stream>>>(W1, W2, W1b, W2b);
    cumsum_kernel<<<dim3(C_DIM), 64, 0, stream>>>(feat, cs_inc);
    transpose_kernel<<<dim3((T_SEQ + 32) / 32, C_DIM / 32), dim3(32, 8), 0, stream>>>(cs_inc, cs_t);
    pool_kernel<<<dim3(N_PROP / 4), 512, 0, stream>>>(cs_t, l, r, e);

    // GEMM1: h = relu(e @ W1^T + b1). 256x128 tile, waves 4x2, 512 blocks (2/CU).
    gemm_hi_kernel<256, 128, 4, 2, K2C, 1>
        <<<dim3((N_PROP / 256) * (HID_DIM / 128)), 512, 0, stream>>>(e, W1b, b1, h, HID_DIM, HID_DIM / 128);
    // GEMM2: out = h @ W2^T + b2. 256x64 tile, waves 8x1, 512 blocks (2/CU).
    gemm_hi_kernel<256, 64, 8, 1, HID_DIM, 0>
        <<<dim3((N_PROP / 256) * (OUT_DIM / 64)), 512, 0, stream>>>(h, W2b, b2, d_out, OUT_DIM, OUT_DIM / 64);
}

// Round 11
// 117.702 us; speedup vs baseline: 1.0262x; 1.0262x over previous
//
#include <hip/hip_runtime.h>
#include <hip/hip_bf16.h>
#include <stdint.h>

#define C_DIM 512
#define T_SEQ 8192
#define N_PROP 16384
#define HID_DIM 1024
#define OUT_DIM 512
#define K2C 1024  // 2*C

typedef __attribute__((ext_vector_type(8))) __bf16 bf16x8;
typedef __attribute__((ext_vector_type(4))) float f32x4;

// ---------------- cumsum: 4 waves per channel, float4 chunks, wave scan + LDS carry ----------------
__global__ __launch_bounds__(256) void cumsum_kernel(const float* __restrict__ feat,
                                                     float* __restrict__ cs_inc) {
    int c = blockIdx.x;
    const float4* in = (const float4*)(feat + (size_t)c * T_SEQ);
    float4* out = (float4*)(cs_inc + (size_t)c * T_SEQ);
    const int lane = threadIdx.x & 63;
    const int w = threadIdx.x >> 6;
    __shared__ float wsum[4];

    float4 v[8];
    float carry = 0.0f;  // lane-uniform within wave
#pragma unroll
    for (int i = 0; i < 8; ++i) {
        float4 t = in[w * 512 + i * 64 + lane];
        float a1 = t.x + t.y;
        float a2 = a1 + t.z;
        float a3 = a2 + t.w;
        float x = a3;
#pragma unroll
        for (int s = 1; s < 64; s <<= 1) {
            float y = __shfl_up(x, s);
            if (lane >= s) x += y;
        }
        float base = carry + (x - a3);
        v[i].x = base + t.x;
        v[i].y = base + a1;
        v[i].z = base + a2;
        v[i].w = base + a3;
        carry += __shfl(x, 63);
    }
    if (lane == 0) wsum[w] = carry;
    __syncthreads();
    float pre = 0.0f;
    for (int j = 0; j < 4; ++j)
        if (j < w) pre += wsum[j];
#pragma unroll
    for (int i = 0; i < 8; ++i) {
        float4 o;
        o.x = v[i].x + pre; o.y = v[i].y + pre; o.z = v[i].z + pre; o.w = v[i].w + pre;
        out[w * 512 + i * 64 + lane] = o;
    }
}

// ---------------- transpose cs_inc (C, T) -> cs_t (T+1, C) with leading-zero shift ----------------
__global__ __launch_bounds__(256) void transpose_kernel(const float* __restrict__ cs_inc,
                                                        float* __restrict__ cs_t) {
    __shared__ float tl[32][33];
    int tx = threadIdx.x, ty = threadIdx.y;  // (32, 8)
    int x0 = blockIdx.x * 32;
    int y0 = blockIdx.y * 32;
#pragma unroll
    for (int i = 0; i < 32; i += 8) {
        int t = x0 + tx;
        int ch = y0 + ty + i;
        float v = 0.0f;
        if (t >= 1 && t <= T_SEQ) v = cs_inc[(size_t)ch * T_SEQ + (t - 1)];
        tl[ty + i][tx] = v;
    }
    __syncthreads();
#pragma unroll
    for (int i = 0; i < 32; i += 8) {
        int t = x0 + ty + i;
        int ch = y0 + tx;
        if (t <= T_SEQ) cs_t[(size_t)t * C_DIM + ch] = tl[tx][ty + i];
    }
}

// ---------------- pooling -> e (N, 2C) bf16; 4 proposals/block, float4/thread ----------------
__global__ __launch_bounds__(512) void pool_kernel(const float* __restrict__ cs_t,
                                                   const int* __restrict__ lptr,
                                                   const int* __restrict__ rptr,
                                                   __hip_bfloat16* __restrict__ e) {
    int n = blockIdx.x * 4 + (threadIdx.x >> 7);
    int c4 = (threadIdx.x & 127) * 4;
    int li = lptr[n], ri = rptr[n];
    float w = fmaxf((float)(ri - li), 1.0f);
    int bw = max(1, (int)(0.15f * w));
    int lb_s = max(0, li - bw);
    int lb_e = min(T_SEQ, li + bw);
    int rb_s = max(0, ri - bw);
    int rb_e = min(T_SEQ, ri + bw);
    lb_e = min(max(lb_s + 1, lb_e), T_SEQ);
    rb_e = min(max(rb_s + 1, rb_e), T_SEQ);
    float4 a = *(const float4*)(cs_t + (size_t)lb_e * C_DIM + c4);
    float4 b = *(const float4*)(cs_t + (size_t)lb_s * C_DIM + c4);
    float4 cc = *(const float4*)(cs_t + (size_t)rb_e * C_DIM + c4);
    float4 d = *(const float4*)(cs_t + (size_t)rb_s * C_DIM + c4);
    float rl = 1.0f / (float)(lb_e - lb_s);
    float rr = 1.0f / (float)(rb_e - rb_s);
    __hip_bfloat16 L0 = __float2bfloat16((a.x - b.x) * rl);
    __hip_bfloat16 L1 = __float2bfloat16((a.y - b.y) * rl);
    __hip_bfloat16 L2 = __float2bfloat16((a.z - b.z) * rl);
    __hip_bfloat16 L3 = __float2bfloat16((a.w - b.w) * rl);
    __hip_bfloat16 R0 = __float2bfloat16((cc.x - d.x) * rr);
    __hip_bfloat16 R1 = __float2bfloat16((cc.y - d.y) * rr);
    __hip_bfloat16 R2 = __float2bfloat16((cc.z - d.z) * rr);
    __hip_bfloat16 R3 = __float2bfloat16((cc.w - d.w) * rr);
    ushort4 ul, ur;
    ul.x = *(unsigned short*)&L0; ul.y = *(unsigned short*)&L1;
    ul.z = *(unsigned short*)&L2; ul.w = *(unsigned short*)&L3;
    ur.x = *(unsigned short*)&R0; ur.y = *(unsigned short*)&R1;
    ur.z = *(unsigned short*)&R2; ur.w = *(unsigned short*)&R3;
    *(ushort4*)(e + (size_t)n * K2C + c4) = ul;
    *(ushort4*)(e + (size_t)n * K2C + C_DIM + c4) = ur;
}

// ---------------- fused fp32 -> bf16 convert for W1 and W2 ----------------
__global__ __launch_bounds__(256) void cvt_bf16_kernel(const float* __restrict__ W1,
                                                       const float* __restrict__ W2,
                                                       __hip_bfloat16* __restrict__ W1b,
                                                       __hip_bfloat16* __restrict__ W2b) {
    const int n1 = HID_DIM * K2C;
    int i = (blockIdx.x * 256 + threadIdx.x) * 4;
    const float* src;
    __hip_bfloat16* dst;
    int j;
    if (i < n1) { src = W1; dst = W1b; j = i; }
    else        { src = W2; dst = W2b; j = i - n1; }
    float4 v = *(const float4*)(src + j);
    __hip_bfloat16 h0 = __float2bfloat16(v.x);
    __hip_bfloat16 h1 = __float2bfloat16(v.y);
    __hip_bfloat16 h2 = __float2bfloat16(v.z);
    __hip_bfloat16 h3 = __float2bfloat16(v.w);
    ushort4 u;
    u.x = *(unsigned short*)&h0; u.y = *(unsigned short*)&h1;
    u.z = *(unsigned short*)&h2; u.w = *(unsigned short*)&h3;
    *(ushort4*)(dst + j) = u;
}

// ---------------- high-intensity dbuf GEMM + K-phase stagger (anti-convoy) ----------------
// C[m][n] = sum_k A[m][k]*B[n][k] (+bias, optional relu->bf16). BK=32, 512 thr = 8 waves.
// R10 structure (best measured), plus: co-resident blocks process K-tiles in ROTATED
// order (phase = resident-slot * NT/2, slot = blockIdx.x>>8 since grid=512 fills the
// 256 CUs twice). K-sum is commutative -> identical result; the rotation decorrelates
// co-resident blocks' stage/barrier windows so their loads mutually hide latency
// (convoy break). A-row-panel-sharing blocks stay same-slot (verified) -> L2 reuse kept.
// GEMM1: 256x128 (waves 4Mx2N, wave 64x64). GEMM2: 256x64 (waves 8Mx1N, wave 32x64).
// Staging: 64B rows (BK=32), 16B granules; both-sides swizzle sigma(row)=row&3.
template <int BM, int BN, int WM, int WN, int K, int RELU_BF16>
__global__ __launch_bounds__(512, 2) void gemm_hi_kernel(const __hip_bfloat16* __restrict__ A,
                                                         const __hip_bfloat16* __restrict__ B,
                                                         const float* __restrict__ bias,
                                                         void* __restrict__ Cout,
                                                         int Nc, int NBlk) {
    constexpr int BK = 32;
    constexpr int NT = K / BK;          // 32 (power of 2)
    constexpr int WMT = BM / WM, WNT = BN / WN;
    constexpr int MR = WMT / 16, NR = WNT / 16;
    constexpr int RA = BM / 128;
    constexpr int RB = BN / 128;
    constexpr bool BHALF = (BN % 128) == 64;

    __shared__ __align__(16) __hip_bfloat16 As[2][BM * BK];
    __shared__ __align__(16) __hip_bfloat16 Bs[2][BN * BK];

    const int tid = threadIdx.x;
    const int lane = tid & 63;
    const int wid = tid >> 6;
    const int wm = wid / WN;
    const int wn = wid % WN;

    const int nwg = gridDim.x;  // 512 (multiple of 8)
    const int wg = (blockIdx.x & 7) * (nwg >> 3) + (blockIdx.x >> 3);
    const long m0 = (long)(wg / NBlk) * BM;
    const long n0 = (long)(wg % NBlk) * BN;

    // anti-convoy K-rotation: resident-slot (0/1) offsets the K-tile sequence by NT/2
    const int phase = ((blockIdx.x >> 8) & 1) * (NT / 2);

    const int srow = tid >> 2;
    const int sgsw = (tid & 3) ^ (srow & 3);
    const int fr = lane & 15;
    const int gq = lane >> 4;

    f32x4 acc[MR][NR] = {};

    auto stage = [&](int s, int k0) {
#pragma unroll
        for (int i = 0; i < RA; ++i)
            __builtin_amdgcn_global_load_lds(
                (const __attribute__((address_space(1))) void*)(A + (m0 + i * 128 + srow) * K + k0 + sgsw * 8),
                (__attribute__((address_space(3))) void*)(&As[s][i * 4096 + tid * 8]), 16, 0, 0);
#pragma unroll
        for (int i = 0; i < RB; ++i)
            __builtin_amdgcn_global_load_lds(
                (const __attribute__((address_space(1))) void*)(B + (n0 + i * 128 + srow) * K + k0 + sgsw * 8),
                (__attribute__((address_space(3))) void*)(&Bs[s][i * 4096 + tid * 8]), 16, 0, 0);
        if constexpr (BHALF) {
            if (tid < 256)
                __builtin_amdgcn_global_load_lds(
                    (const __attribute__((address_space(1))) void*)(B + (n0 + srow) * K + k0 + sgsw * 8),
                    (__attribute__((address_space(3))) void*)(&Bs[s][tid * 8]), 16, 0, 0);
        }
    };
    auto ldA = [&](int s, int row) -> bf16x8 {
        return *(const bf16x8*)(&As[s][row * BK + ((gq ^ (row & 3)) * 8)]);
    };
    auto ldB = [&](int s, int row) -> bf16x8 {
        return *(const bf16x8*)(&Bs[s][row * BK + ((gq ^ (row & 3)) * 8)]);
    };

    stage(0, phase * BK);
    __syncthreads();
    for (int t = 0; t < NT; ++t) {
        const int cur = t & 1;
        if (t + 1 < NT) stage(cur ^ 1, (((t + 1 + phase) & (NT - 1)) * BK));
        bf16x8 af[MR], bv[NR];
#pragma unroll
        for (int m = 0; m < MR; ++m) af[m] = ldA(cur, wm * WMT + m * 16 + fr);
#pragma unroll
        for (int n = 0; n < NR; ++n) bv[n] = ldB(cur, wn * WNT + n * 16 + fr);
#pragma unroll
        for (int m = 0; m < MR; ++m)
#pragma unroll
            for (int n = 0; n < NR; ++n)
                acc[m][n] = __builtin_amdgcn_mfma_f32_16x16x32_bf16(af[m], bv[n], acc[m][n], 0, 0, 0);
        __syncthreads();
    }

    const int rq = (lane >> 4) * 4;
#pragma unroll
    for (int m = 0; m < MR; ++m)
#pragma unroll
        for (int n = 0; n < NR; ++n) {
            long col = n0 + wn * WNT + n * 16 + fr;
            float bb = bias[col];
#pragma unroll
            for (int q = 0; q < 4; ++q) {
                long row = m0 + wm * WMT + m * 16 + rq + q;
                float v = acc[m][n][q] + bb;
                if (RELU_BF16) {
                    v = fmaxf(v, 0.0f);
                    ((__hip_bfloat16*)Cout)[row * Nc + col] = __float2bfloat16(v);
                } else {
                    ((float*)Cout)[row * Nc + col] = v;
                }
            }
        }
}

extern "C" void kernel_launch(void* const* d_in, const int* in_sizes, int n_in,
                              void* d_out, int out_size, void* d_ws, size_t ws_size,
                              hipStream_t stream) {
    const float* feat = (const float*)d_in[0];
    const int* l = (const int*)d_in[1];
    const int* r = (const int*)d_in[2];
    const float* W1 = (const float*)d_in[4];
    const float* b1 = (const float*)d_in[5];
    const float* W2 = (const float*)d_in[6];
    const float* b2 = (const float*)d_in[7];

    char* ws = (char*)d_ws;
    float* cs_t = (float*)ws;                                    // 8193*512*4
    __hip_bfloat16* e = (__hip_bfloat16*)(ws + 16779264);        // 16384*1024*2
    __hip_bfloat16* h = (__hip_bfloat16*)(ws + 50333696);        // 16384*1024*2 (aliases cs_inc)
    float* cs_inc = (float*)(ws + 50333696);                     // 512*8192*4, dead before h
    __hip_bfloat16* W1b = (__hip_bfloat16*)(ws + 83888128);      // 1024*1024*2
    __hip_bfloat16* W2b = (__hip_bfloat16*)(ws + 85985280);      // 512*1024*2

    const int ncvt = (HID_DIM * K2C + OUT_DIM * HID_DIM) / 4 / 256;
    cvt_bf16_kernel<<<dim3(ncvt), 256, 0, stream>>>(W1, W2, W1b, W2b);
    cumsum_kernel<<<dim3(C_DIM), 256, 0, stream>>>(feat, cs_inc);
    transpose_kernel<<<dim3((T_SEQ + 32) / 32, C_DIM / 32), dim3(32, 8), 0, stream>>>(cs_inc, cs_t);
    pool_kernel<<<dim3(N_PROP / 4), 512, 0, stream>>>(cs_t, l, r, e);

    // GEMM1: h = relu(e @ W1^T + b1). 256x128 tile, waves 4x2, 512 blocks (2/CU).
    gemm_hi_kernel<256, 128, 4, 2, K2C, 1>
        <<<dim3((N_PROP / 256) * (HID_DIM / 128)), 512, 0, stream>>>(e, W1b, b1, h, HID_DIM, HID_DIM / 128);
    // GEMM2: out = h @ W2^T + b2. 256x64 tile, waves 8x1, 512 blocks (2/CU).
    gemm_hi_kernel<256, 64, 8, 1, HID_DIM, 0>
        <<<dim3((N_PROP / 256) * (OUT_DIM / 64)), 512, 0, stream>>>(h, W2b, b2, d_out, OUT_DIM, OUT_DIM / 64);
}

// Round 12
// 113.685 us; speedup vs baseline: 1.0625x; 1.0353x over previous
//
#include <hip/hip_runtime.h>
#include <hip/hip_bf16.h>
#include <stdint.h>

#define C_DIM 512
#define T_SEQ 8192
#define N_PROP 16384
#define HID_DIM 1024
#define OUT_DIM 512
#define K2C 1024  // 2*C

typedef __attribute__((ext_vector_type(8))) __bf16 bf16x8;
typedef __attribute__((ext_vector_type(4))) float f32x4;

#define BAR() __builtin_amdgcn_s_barrier()
#define LGKM0_SB() do { asm volatile("s_waitcnt lgkmcnt(0)" ::: "memory"); __builtin_amdgcn_sched_barrier(0); } while (0)

// ---------------- cumsum: 4 waves per channel, float4 chunks, wave scan + LDS carry ----------------
__global__ __launch_bounds__(256) void cumsum_kernel(const float* __restrict__ feat,
                                                     float* __restrict__ cs_inc) {
    int c = blockIdx.x;
    const float4* in = (const float4*)(feat + (size_t)c * T_SEQ);
    float4* out = (float4*)(cs_inc + (size_t)c * T_SEQ);
    const int lane = threadIdx.x & 63;
    const int w = threadIdx.x >> 6;
    __shared__ float wsum[4];

    float4 v[8];
    float carry = 0.0f;
#pragma unroll
    for (int i = 0; i < 8; ++i) {
        float4 t = in[w * 512 + i * 64 + lane];
        float a1 = t.x + t.y;
        float a2 = a1 + t.z;
        float a3 = a2 + t.w;
        float x = a3;
#pragma unroll
        for (int s = 1; s < 64; s <<= 1) {
            float y = __shfl_up(x, s);
            if (lane >= s) x += y;
        }
        float base = carry + (x - a3);
        v[i].x = base + t.x;
        v[i].y = base + a1;
        v[i].z = base + a2;
        v[i].w = base + a3;
        carry += __shfl(x, 63);
    }
    if (lane == 0) wsum[w] = carry;
    __syncthreads();
    float pre = 0.0f;
    for (int j = 0; j < 4; ++j)
        if (j < w) pre += wsum[j];
#pragma unroll
    for (int i = 0; i < 8; ++i) {
        float4 o;
        o.x = v[i].x + pre; o.y = v[i].y + pre; o.z = v[i].z + pre; o.w = v[i].w + pre;
        out[w * 512 + i * 64 + lane] = o;
    }
}

// ---------------- transpose cs_inc (C, T) -> cs_t (T+1, C) with leading-zero shift ----------------
__global__ __launch_bounds__(256) void transpose_kernel(const float* __restrict__ cs_inc,
                                                        float* __restrict__ cs_t) {
    __shared__ float tl[32][33];
    int tx = threadIdx.x, ty = threadIdx.y;  // (32, 8)
    int x0 = blockIdx.x * 32;
    int y0 = blockIdx.y * 32;
#pragma unroll
    for (int i = 0; i < 32; i += 8) {
        int t = x0 + tx;
        int ch = y0 + ty + i;
        float v = 0.0f;
        if (t >= 1 && t <= T_SEQ) v = cs_inc[(size_t)ch * T_SEQ + (t - 1)];
        tl[ty + i][tx] = v;
    }
    __syncthreads();
#pragma unroll
    for (int i = 0; i < 32; i += 8) {
        int t = x0 + ty + i;
        int ch = y0 + tx;
        if (t <= T_SEQ) cs_t[(size_t)t * C_DIM + ch] = tl[tx][ty + i];
    }
}

// ---------------- pooling -> e (N, 2C) bf16; 4 proposals/block, float4/thread ----------------
__global__ __launch_bounds__(512) void pool_kernel(const float* __restrict__ cs_t,
                                                   const int* __restrict__ lptr,
                                                   const int* __restrict__ rptr,
                                                   __hip_bfloat16* __restrict__ e) {
    int n = blockIdx.x * 4 + (threadIdx.x >> 7);
    int c4 = (threadIdx.x & 127) * 4;
    int li = lptr[n], ri = rptr[n];
    float w = fmaxf((float)(ri - li), 1.0f);
    int bw = max(1, (int)(0.15f * w));
    int lb_s = max(0, li - bw);
    int lb_e = min(T_SEQ, li + bw);
    int rb_s = max(0, ri - bw);
    int rb_e = min(T_SEQ, ri + bw);
    lb_e = min(max(lb_s + 1, lb_e), T_SEQ);
    rb_e = min(max(rb_s + 1, rb_e), T_SEQ);
    float4 a = *(const float4*)(cs_t + (size_t)lb_e * C_DIM + c4);
    float4 b = *(const float4*)(cs_t + (size_t)lb_s * C_DIM + c4);
    float4 cc = *(const float4*)(cs_t + (size_t)rb_e * C_DIM + c4);
    float4 d = *(const float4*)(cs_t + (size_t)rb_s * C_DIM + c4);
    float rl = 1.0f / (float)(lb_e - lb_s);
    float rr = 1.0f / (float)(rb_e - rb_s);
    __hip_bfloat16 L0 = __float2bfloat16((a.x - b.x) * rl);
    __hip_bfloat16 L1 = __float2bfloat16((a.y - b.y) * rl);
    __hip_bfloat16 L2 = __float2bfloat16((a.z - b.z) * rl);
    __hip_bfloat16 L3 = __float2bfloat16((a.w - b.w) * rl);
    __hip_bfloat16 R0 = __float2bfloat16((cc.x - d.x) * rr);
    __hip_bfloat16 R1 = __float2bfloat16((cc.y - d.y) * rr);
    __hip_bfloat16 R2 = __float2bfloat16((cc.z - d.z) * rr);
    __hip_bfloat16 R3 = __float2bfloat16((cc.w - d.w) * rr);
    ushort4 ul, ur;
    ul.x = *(unsigned short*)&L0; ul.y = *(unsigned short*)&L1;
    ul.z = *(unsigned short*)&L2; ul.w = *(unsigned short*)&L3;
    ur.x = *(unsigned short*)&R0; ur.y = *(unsigned short*)&R1;
    ur.z = *(unsigned short*)&R2; ur.w = *(unsigned short*)&R3;
    *(ushort4*)(e + (size_t)n * K2C + c4) = ul;
    *(ushort4*)(e + (size_t)n * K2C + C_DIM + c4) = ur;
}

// ---------------- fused fp32 -> bf16 convert for W1 and W2 ----------------
__global__ __launch_bounds__(256) void cvt_bf16_kernel(const float* __restrict__ W1,
                                                       const float* __restrict__ W2,
                                                       __hip_bfloat16* __restrict__ W1b,
                                                       __hip_bfloat16* __restrict__ W2b) {
    const int n1 = HID_DIM * K2C;
    int i = (blockIdx.x * 256 + threadIdx.x) * 4;
    const float* src;
    __hip_bfloat16* dst;
    int j;
    if (i < n1) { src = W1; dst = W1b; j = i; }
    else        { src = W2; dst = W2b; j = i - n1; }
    float4 v = *(const float4*)(src + j);
    __hip_bfloat16 h0 = __float2bfloat16(v.x);
    __hip_bfloat16 h1 = __float2bfloat16(v.y);
    __hip_bfloat16 h2 = __float2bfloat16(v.z);
    __hip_bfloat16 h3 = __float2bfloat16(v.w);
    ushort4 u;
    u.x = *(unsigned short*)&h0; u.y = *(unsigned short*)&h1;
    u.z = *(unsigned short*)&h2; u.w = *(unsigned short*)&h3;
    *(ushort4*)(dst + j) = u;
}

// ---------------- m201-faithful 8-phase half-tile GEMM ----------------
// C[m][n] = sum_k A[m][k]*B[n][k] (+bias, optional relu->bf16).
// BM=256, BK=64, 512 thr = 8 waves (2M x 4N); wave tile 128 x (BN/4); MR=8.
// Iter = 2 K-tiles (u0=2i buf0, u1=2i+1 buf1), 8 phases; per phase:
//   {4-8 ds_read quadrant ; stage ONE half-tile ; BAR ; lgkmcnt0+schedbar ;
//    setprio(1) 16/8 MFMA setprio(0) ; [vmcnt publish ph3/ph7] ; BAR}
// Quadrant(kk, A-half): B frags read only at kk-entry phases (ph0/2/4/6).
// Half-tiles: A0/A1 = 128 tile-rows of A (2 rounds), B0/B1 = BN/2 rows (RBH rounds).
// Stage stream (WAR-audited: each target slot's last ds_read >= 1 phase before issue):
//   ph0:B1(u1) ph1:A0(u1) ph2:A1(u1) ph3:B0(u+2) ph4:B1(u+2) ph5:A0(u+2)
//   ph6:A1(u+2) ph7:B0(u+3)
// Publish (wait-then-barrier, R5 discipline): end-ph3 vmcnt(RBH) -> tile u1 landed;
// end-ph7 vmcnt(RBH) -> tile u+2 landed. Tail iter: vmcnt(0). Prologue: tile0 full +
// B0(t1); vmcnt(RBH); BAR.
template <int BN, int K, int RELU_BF16>
__global__ __launch_bounds__(512, 1) void gemm_hk_kernel(const __hip_bfloat16* __restrict__ A,
                                                         const __hip_bfloat16* __restrict__ B,
                                                         const float* __restrict__ bias,
                                                         void* __restrict__ Cout,
                                                         int Nc, int NBlk) {
    constexpr int BM = 256, BK = 64;
    constexpr int NT = K / BK, NI = NT / 2;
    constexpr int WNT = BN / 4;
    constexpr int NR = WNT / 16;       // 4 (GEMM1) / 2 (GEMM2)
    constexpr int RBH = BN / 128;      // rounds per B-half: 2 / 1
    constexpr int BHR = BN / 2;        // rows per B-half

    __shared__ __align__(16) __hip_bfloat16 As[2][BM * BK];
    __shared__ __align__(16) __hip_bfloat16 Bs[2][BN * BK];

    const int tid = threadIdx.x;
    const int lane = tid & 63;
    const int wid = tid >> 6;
    const int wm = wid >> 2;           // 0..1
    const int wn = wid & 3;            // 0..3

    const int nwg = gridDim.x;         // 256
    const int wg = (blockIdx.x & 7) * (nwg >> 3) + (blockIdx.x >> 3);
    const long m0 = (long)(wg / NBlk) * BM;
    const long n0 = (long)(wg % NBlk) * BN;

    const int srow = tid >> 3;                  // 64 rows/round
    const int schunk = (tid & 7) ^ (srow & 7);  // pre-swizzled source granule (T2)
    const int fr = lane & 15;
    const int g8 = (lane >> 4) * 8;

    f32x4 acc[8][NR] = {};

    auto stA = [&](int d, int h, long kel) {  // A-half h: 2 rounds of 64 rows
#pragma unroll
        for (int r2 = 0; r2 < 2; ++r2)
            __builtin_amdgcn_global_load_lds(
                (const __attribute__((address_space(1))) void*)(A + (m0 + h * 128 + r2 * 64 + srow) * K + kel + schunk * 8),
                (__attribute__((address_space(3))) void*)(&As[d][(h * 128 + r2 * 64) * 64 + tid * 8]), 16, 0, 0);
    };
    auto stB = [&](int d, int h, long kel) {  // B-half h: RBH rounds
#pragma unroll
        for (int r2 = 0; r2 < RBH; ++r2)
            __builtin_amdgcn_global_load_lds(
                (const __attribute__((address_space(1))) void*)(B + (n0 + h * BHR + r2 * 64 + srow) * K + kel + schunk * 8),
                (__attribute__((address_space(3))) void*)(&Bs[d][(h * BHR + r2 * 64) * 64 + tid * 8]), 16, 0, 0);
    };
    auto ldf = [&](const __hip_bfloat16* buf, int row, int kb) -> bf16x8 {
        return *(const bf16x8*)(&buf[row * 64 + ((kb + g8) ^ ((row & 7) * 8))]);
    };
    auto rdA = [&](int d, int mlo, int kb, bf16x8* af) {
#pragma unroll
        for (int m = 0; m < 4; ++m) af[m] = ldf(&As[d][0], wm * 128 + (mlo + m) * 16 + fr, kb);
    };
    auto rdB = [&](int d, int kb, bf16x8* bv) {
#pragma unroll
        for (int n = 0; n < NR; ++n) bv[n] = ldf(&Bs[d][0], wn * WNT + n * 16 + fr, kb);
    };
    auto mf4 = [&](const bf16x8* af, const bf16x8* bv, int mlo) {
        __builtin_amdgcn_s_setprio(1);
#pragma unroll
        for (int m = 0; m < 4; ++m)
#pragma unroll
            for (int n = 0; n < NR; ++n)
                acc[mlo + m][n] = __builtin_amdgcn_mfma_f32_16x16x32_bf16(af[m], bv[n], acc[mlo + m][n], 0, 0, 0);
        __builtin_amdgcn_s_setprio(0);
    };

    // ---- prologue: tile0 {A0,A1,B0,B1} + B0(t1); publish tile0 ----
    stA(0, 0, 0); stA(0, 1, 0); stB(0, 0, 0); stB(0, 1, 0);
    stB(1, 0, BK);
    asm volatile("s_waitcnt vmcnt(%0)" ::"n"(RBH) : "memory");
    BAR();

    bf16x8 afA[4], afB[4], bv[NR];

#pragma unroll 1
    for (int i = 0; i < NI; ++i) {
        const bool more = (i + 1 < NI);
        const long kU1 = (2L * i + 1) * BK;
        const long kE = (2L * i + 2) * BK;
        const long kO = (2L * i + 3) * BK;

        // ---- ph0: buf0 (kk0, A-half lo) + B kk0 ----
        rdA(0, 0, 0, afA); rdB(0, 0, bv);
        stB(1, 1, kU1);
        BAR(); LGKM0_SB();
        mf4(afA, bv, 0);
        BAR();
        // ---- ph1: (kk0, A-half hi) ----
        rdA(0, 4, 0, afB);
        stA(1, 0, kU1);
        BAR(); LGKM0_SB();
        mf4(afB, bv, 4);
        BAR();
        // ---- ph2: (kk1, lo) + B kk1 ----
        rdA(0, 0, 32, afA); rdB(0, 32, bv);
        stA(1, 1, kU1);
        BAR(); LGKM0_SB();
        mf4(afA, bv, 0);
        BAR();
        // ---- ph3: (kk1, hi); publish tile u1 ----
        rdA(0, 4, 32, afB);
        if (more) stB(0, 0, kE);
        BAR(); LGKM0_SB();
        mf4(afB, bv, 4);
        if (more) asm volatile("s_waitcnt vmcnt(%0)" ::"n"(RBH) : "memory");
        else      asm volatile("s_waitcnt vmcnt(0)" ::: "memory");
        BAR();
        // ---- ph4: buf1 (kk0, lo) + B kk0 ----
        rdA(1, 0, 0, afA); rdB(1, 0, bv);
        if (more) stB(0, 1, kE);
        BAR(); LGKM0_SB();
        mf4(afA, bv, 0);
        BAR();
        // ---- ph5: (kk0, hi) ----
        rdA(1, 4, 0, afB);
        if (more) stA(0, 0, kE);
        BAR(); LGKM0_SB();
        mf4(afB, bv, 4);
        BAR();
        // ---- ph6: (kk1, lo) + B kk1 ----
        rdA(1, 0, 32, afA); rdB(1, 32, bv);
        if (more) stA(0, 1, kE);
        BAR(); LGKM0_SB();
        mf4(afA, bv, 0);
        BAR();
        // ---- ph7: (kk1, hi); publish tile u+2 ----
        rdA(1, 4, 32, afB);
        if (more) stB(1, 0, kO);
        BAR(); LGKM0_SB();
        mf4(afB, bv, 4);
        if (more) asm volatile("s_waitcnt vmcnt(%0)" ::"n"(RBH) : "memory");
        else      asm volatile("s_waitcnt vmcnt(0)" ::: "memory");
        BAR();
    }

    const int rq = (lane >> 4) * 4;
#pragma unroll
    for (int m = 0; m < 8; ++m)
#pragma unroll
        for (int n = 0; n < NR; ++n) {
            long col = n0 + wn * WNT + n * 16 + fr;
            float bb = bias[col];
#pragma unroll
            for (int q = 0; q < 4; ++q) {
                long row = m0 + wm * 128 + m * 16 + rq + q;
                float v = acc[m][n][q] + bb;
                if (RELU_BF16) {
                    v = fmaxf(v, 0.0f);
                    ((__hip_bfloat16*)Cout)[row * Nc + col] = __float2bfloat16(v);
                } else {
                    ((float*)Cout)[row * Nc + col] = v;
                }
            }
        }
}

extern "C" void kernel_launch(void* const* d_in, const int* in_sizes, int n_in,
                              void* d_out, int out_size, void* d_ws, size_t ws_size,
                              hipStream_t stream) {
    const float* feat = (const float*)d_in[0];
    const int* l = (const int*)d_in[1];
    const int* r = (const int*)d_in[2];
    const float* W1 = (const float*)d_in[4];
    const float* b1 = (const float*)d_in[5];
    const float* W2 = (const float*)d_in[6];
    const float* b2 = (const float*)d_in[7];

    char* ws = (char*)d_ws;
    float* cs_t = (float*)ws;                                    // 8193*512*4
    __hip_bfloat16* e = (__hip_bfloat16*)(ws + 16779264);        // 16384*1024*2
    __hip_bfloat16* h = (__hip_bfloat16*)(ws + 50333696);        // 16384*1024*2 (aliases cs_inc)
    float* cs_inc = (float*)(ws + 50333696);                     // 512*8192*4, dead before h
    __hip_bfloat16* W1b = (__hip_bfloat16*)(ws + 83888128);      // 1024*1024*2
    __hip_bfloat16* W2b = (__hip_bfloat16*)(ws + 85985280);      // 512*1024*2

    const int ncvt = (HID_DIM * K2C + OUT_DIM * HID_DIM) / 4 / 256;
    cvt_bf16_kernel<<<dim3(ncvt), 256, 0, stream>>>(W1, W2, W1b, W2b);
    cumsum_kernel<<<dim3(C_DIM), 256, 0, stream>>>(feat, cs_inc);
    transpose_kernel<<<dim3((T_SEQ + 32) / 32, C_DIM / 32), dim3(32, 8), 0, stream>>>(cs_inc, cs_t);
    pool_kernel<<<dim3(N_PROP / 4), 512, 0, stream>>>(cs_t, l, r, e);

    // GEMM1: h = relu(e @ W1^T + b1). 256x256, 256 blocks (1/CU), LDS 128 KB.
    gemm_hk_kernel<256, K2C, 1>
        <<<dim3((N_PROP / 256) * (HID_DIM / 256)), 512, 0, stream>>>(e, W1b, b1, h, HID_DIM, HID_DIM / 256);
    // GEMM2: out = h @ W2^T + b2. 256x128, 256 blocks (1/CU), LDS 96 KB.
    gemm_hk_kernel<128, HID_DIM, 0>
        <<<dim3((N_PROP / 256) * (OUT_DIM / 128)), 512, 0, stream>>>(h, W2b, b2, d_out, OUT_DIM, OUT_DIM / 128);
}